// Round 7
// baseline (214.010 us; speedup 1.0000x reference)
//
#include <hip/hip_runtime.h>
#include <hip/hip_bf16.h>
#include <math.h>

// Problem constants
#define Bb 4
#define Nn 1025
#define Cc 768
#define Hh 12
#define BH (Bb*Hh)          // 48
#define M_ROWS 4100
#define KSEL 256            // int(1024*0.25)
#define JP 1152             // padded j (9 sweeps x 128)
#define IT_TILES 68         // qB i-tiles of 16 (i < 1088)
#define NIB32 33            // colsum i-blocks of 32
#define NSW 9               // j-sweeps of 128
#define MT16 264            // padded M tiles of 16 (4224 rows)
#define KC24 24             // 768/32 k-chunks
#define JT16 72             // j 16-tiles (1152/16)
#define JT32 36             // j 32-tiles (1152/32) for V K=32 B-frags
#define STR4 292            // expS8 row stride in u32 (288 used + 4 pad)
#define NPART 396           // partial rows per batch (12 h * 33 ib)
#define NSCORE 1024         // patch tokens scored per batch
#define QSCALE 0.18033688011112042f   // 0.125 * log2(e): S is in log2 domain
#define MBIAS -30000.0f     // log2-domain mask: exp2(-30000+S) == 0.0 exactly

// cast_all region sizes (in 256-thread blocks)
#define CAST_X_BLK 1584     // 405,504 slots
#define CAST_WQKV_BLK 864   // 221,184 slots
#define CAST_WPROJ_BLK 288  // 73,728 slots

typedef __attribute__((ext_vector_type(8))) short short8;
typedef __attribute__((ext_vector_type(4))) float floatx4;
typedef __attribute__((ext_vector_type(4))) unsigned uintx4;

static __device__ inline unsigned short f2bf(float v) {       // RNE
    __hip_bfloat16 b = __float2bfloat16(v);
    return *reinterpret_cast<unsigned short*>(&b);
}
static __device__ inline float fexp2(float x) {
    return __builtin_amdgcn_exp2f(x);
}
// pack two f32 -> bf16x2 u32 by truncation (lo = first arg)
static __device__ inline unsigned pkbf(float lo, float hi) {
    union { float f; unsigned u; } a, b;
    a.f = lo; b.f = hi;
    return (a.u >> 16) | (b.u & 0xffff0000u);
}

// async global->LDS, 16B per lane; lds dest must be wave-uniform base
static __device__ inline void async16(const unsigned short* g, unsigned short* l) {
    __builtin_amdgcn_global_load_lds(
        (const __attribute__((address_space(1))) unsigned int*)g,
        (__attribute__((address_space(3))) unsigned int*)l, 16, 0, 0);
}

// ---------------------------------------------------------------------------
// Fused input casts: x -> xA (A-frag), Wqkv -> WB (B-frag), Wproj -> WpB.
__global__ __launch_bounds__(256)
void cast_all(const float* __restrict__ x, const float* __restrict__ Wqkv,
              const float* __restrict__ Wproj,
              unsigned short* __restrict__ xA, unsigned short* __restrict__ WB,
              unsigned short* __restrict__ WpB)
{
    int blk = blockIdx.x;
    int tid = threadIdx.x;
    if (blk < CAST_X_BLK) {
        int s = blk * 256 + tid;                    // < 405504
        int ml = s & 15, q = (s >> 4) & 3;
        int t2 = s >> 6;
        int mt = t2 % MT16, kc = t2 / MT16;
        int m = mt * 16 + ml, k = kc * 32 + q * 8;
        uint4 pk = {0u, 0u, 0u, 0u};
        if (m < M_ROWS) {
            float4 a = *(const float4*)&x[(size_t)m * 768 + k];
            float4 b2 = *(const float4*)&x[(size_t)m * 768 + k + 4];
            pk.x = (unsigned)f2bf(a.x)  | ((unsigned)f2bf(a.y)  << 16);
            pk.y = (unsigned)f2bf(a.z)  | ((unsigned)f2bf(a.w)  << 16);
            pk.z = (unsigned)f2bf(b2.x) | ((unsigned)f2bf(b2.y) << 16);
            pk.w = (unsigned)f2bf(b2.z) | ((unsigned)f2bf(b2.w) << 16);
        }
        *(uint4*)&xA[(size_t)s * 8] = pk;
        return;
    }
    const float* W;
    unsigned short* WO;
    int N, NT, s;
    if (blk < CAST_X_BLK + CAST_WQKV_BLK) {
        W = Wqkv; WO = WB; N = 2304; NT = 144;
        s = (blk - CAST_X_BLK) * 256 + tid;
    } else {
        W = Wproj; WO = WpB; N = 768; NT = 48;
        s = (blk - CAST_X_BLK - CAST_WQKV_BLK) * 256 + tid;
    }
    int nl = s & 15, q = (s >> 4) & 3;
    int t2 = s >> 6;
    int nt = t2 % NT, kc = t2 / NT;
    int n = nt * 16 + nl, k = kc * 32 + q * 8;
    unsigned hv[8];
#pragma unroll
    for (int e = 0; e < 8; ++e)
        hv[e] = f2bf(W[(size_t)(k + e) * N + n]);
    uint4 pk;
    pk.x = hv[0] | (hv[1] << 16);
    pk.y = hv[2] | (hv[3] << 16);
    pk.z = hv[4] | (hv[5] << 16);
    pk.w = hv[6] | (hv[7] << 16);
    *(uint4*)&WO[(size_t)s * 8] = pk;
}

// ---------------------------------------------------------------------------
// MFMA bf16 GEMM, 128x(NT*32) tile, 4 waves x (4xNT of 16x16x32), BK=32.
template<int NT, int MODE>
__global__ __launch_bounds__(256, 3)
void gemm_mfma(const unsigned short* __restrict__ Af,
               const unsigned short* __restrict__ Bf,
               int Nt16,
               unsigned short* __restrict__ qB, unsigned short* __restrict__ kF,
               unsigned short* __restrict__ vF,
               float* __restrict__ outp, const float* __restrict__ bias)
{
    __shared__ __align__(16) unsigned short ldsA[4096];
    __shared__ __align__(16) unsigned short ldsB[NT * 1024];
    const int tid = threadIdx.x;
    const int ln = tid & 63, w = tid >> 6;
    const int wm = w >> 1, wn = w & 1;
    const int mb = blockIdx.x, nb = blockIdx.y;

    floatx4 acc[4][NT];
#pragma unroll
    for (int mt = 0; mt < 4; ++mt)
#pragma unroll
        for (int nt = 0; nt < NT; ++nt)
            acc[mt][nt] = (floatx4){0.f, 0.f, 0.f, 0.f};

    for (int kc = 0; kc < KC24; ++kc) {
        const unsigned short* gA = Af + ((size_t)(kc * MT16 + mb * 8)) * 512;
        const unsigned short* gB = Bf + ((size_t)(kc * Nt16 + nb * (NT * 2))) * 512;
        async16(gA + (size_t)(w * 128 + ln) * 8,      &ldsA[w * 1024]);
        async16(gA + (size_t)(w * 128 + 64 + ln) * 8, &ldsA[w * 1024 + 512]);
        if (NT == 4) {
            async16(gB + (size_t)(w * 128 + ln) * 8,      &ldsB[w * 1024]);
            async16(gB + (size_t)(w * 128 + 64 + ln) * 8, &ldsB[w * 1024 + 512]);
        } else {
            async16(gB + (size_t)(w * 64 + ln) * 8, &ldsB[w * 512]);
        }
        __syncthreads();

        short8 Am[4], Bn[NT];
#pragma unroll
        for (int mt = 0; mt < 4; ++mt)
            Am[mt] = *(const short8*)&ldsA[((wm * 4 + mt) * 64 + ln) * 8];
#pragma unroll
        for (int nt = 0; nt < NT; ++nt)
            Bn[nt] = *(const short8*)&ldsB[((wn * NT + nt) * 64 + ln) * 8];
#pragma unroll
        for (int mt = 0; mt < 4; ++mt)
#pragma unroll
            for (int nt = 0; nt < NT; ++nt)
                acc[mt][nt] = __builtin_amdgcn_mfma_f32_16x16x32_bf16(
                    Am[mt], Bn[nt], acc[mt][nt], 0, 0, 0);
        __syncthreads();
    }

    const int q = ln >> 4, l15 = ln & 15;
    if (MODE == 1) {
#pragma unroll
        for (int nt = 0; nt < NT; ++nt) {
            int gn = nb * (NT * 32) + wn * (NT * 16) + nt * 16 + l15;
            float bv = bias[gn];
#pragma unroll
            for (int mt = 0; mt < 4; ++mt) {
                int gmb = mb * 128 + wm * 64 + mt * 16 + q * 4;
#pragma unroll
                for (int r = 0; r < 4; ++r) {
                    int gm = gmb + r;
                    if (gm < M_ROWS)
                        outp[(size_t)gm * 768 + gn] = acc[mt][nt][r] + bv;
                }
            }
        }
    } else {
#pragma unroll
        for (int nt = 0; nt < NT; ++nt) {
            int gn = nb * (NT * 32) + wn * (NT * 16) + nt * 16 + l15;
            int s = (gn >= 1536) ? 2 : (gn >= 768 ? 1 : 0);
            int rr = gn - s * Cc;
            int h = rr >> 6, d = rr & 63;
#pragma unroll
            for (int mt = 0; mt < 4; ++mt) {
                int gmb = mb * 128 + wm * 64 + mt * 16 + q * 4;
#pragma unroll
                for (int r = 0; r < 4; ++r) {
                    int gm = gmb + r;
                    if (gm >= M_ROWS) continue;
                    int b = gm / Nn;
                    int n = gm - b * Nn;
                    int bh = b * Hh + h;
                    float val = acc[mt][nt][r];
                    if (s == 0) {
                        int idx = (((bh * IT_TILES + (n >> 4)) * 2 + (d >> 5)) * 512)
                                  + ((((d & 31) >> 3) * 16 + (n & 15)) * 8) + (d & 7);
                        qB[idx] = f2bf(val * QSCALE);
                    } else if (s == 1) {
                        size_t idx = ((((size_t)bh * JT16 + (n >> 4)) * 2 + (d >> 5)) * 64
                                      + ((d >> 3) & 3) * 16 + (n & 15)) * 8 + (d & 7);
                        kF[idx] = f2bf(val);
                    } else {
                        // V as 16x16x32 B-frag per 32-j group
                        size_t idx = ((((size_t)bh * JT32 + (n >> 5)) * 4 + (d >> 4)) * 64
                                      + ((n >> 3) & 3) * 16 + (d & 15)) * 8 + (n & 7);
                        vF[idx] = f2bf(val);
                    }
                }
            }
        }
    }
}

// ---------------------------------------------------------------------------
// Pass A: SINGLE-QK colsum (expS as fp8 e4m3 in LDS, 4 blocks/CU).
// Valid-mask multiply applied only in the last sweep (identity for sw<8).
__global__ __launch_bounds__(256, 4)
void attn_colsum_mfma(const unsigned short* __restrict__ qB,
                      const unsigned short* __restrict__ kF,
                      float* __restrict__ colsum_part)
{
    __shared__ unsigned int expS8[32 * STR4];     // 37,376 B  fp8 [i][j/4]
    __shared__ float red16[16][32];               // 2,048 B
    __shared__ float linv[32];

    const int blk = blockIdx.x;                 // 1584 = 8 * 198
    const int x8 = blk & 7, g = blk >> 3;
    const int bh = x8 * 6 + (g % 6);
    const int ib = g / 6;                        // 0..32
    const int tid = threadIdx.x;
    const int ws = tid >> 6;
    const int ln = tid & 63;
    const int i16 = ln & 15, q = ln >> 4;

    const unsigned short* kBase = kF + (size_t)bh * JT16 * 1024;

    short8 Qf[2][2];
#pragma unroll
    for (int it = 0; it < 2; ++it)
#pragma unroll
        for (int kc = 0; kc < 2; ++kc)
            Qf[it][kc] = *(const short8*)&qB[(((size_t)bh * IT_TILES + ib * 2 + it) * 2 + kc) * 512 + ln * 8];

    float lacc[2][2] = {{0.f, 0.f}, {0.f, 0.f}};

    short8 Kc[2][2], Kn[2][2];
#pragma unroll
    for (int jt = 0; jt < 2; ++jt)
#pragma unroll
        for (int kc = 0; kc < 2; ++kc)
            Kc[jt][kc] = *(const short8*)&kBase[(((ws * 2 + jt) * 2 + kc) * 64 + ln) * 8];

    for (int sw = 0; sw < NSW; ++sw) {
        if (sw + 1 < NSW) {
#pragma unroll
            for (int jt = 0; jt < 2; ++jt)
#pragma unroll
                for (int kc = 0; kc < 2; ++kc)
                    Kn[jt][kc] = *(const short8*)&kBase[((((sw + 1) * 8 + ws * 2 + jt) * 2 + kc) * 64 + ln) * 8];
        }

        floatx4 S[2][2];
#pragma unroll
        for (int it = 0; it < 2; ++it)
#pragma unroll
            for (int jt = 0; jt < 2; ++jt) {
                S[it][jt] = (floatx4){0.f, 0.f, 0.f, 0.f};
#pragma unroll
                for (int kc = 0; kc < 2; ++kc)
                    S[it][jt] = __builtin_amdgcn_mfma_f32_16x16x32_bf16(Kc[jt][kc], Qf[it][kc], S[it][jt], 0, 0, 0);
            }

        const int jbase0 = sw * 128 + ws * 32 + q * 4;
#pragma unroll
        for (int it = 0; it < 2; ++it) {
            const int irow = it * 16 + i16;
#pragma unroll
            for (int jt = 0; jt < 2; ++jt) {
                int jbase = jbase0 + jt * 16;
                float p[4];
                if (sw < NSW - 1) {
#pragma unroll
                    for (int r = 0; r < 4; ++r)
                        p[r] = fexp2(S[it][jt][r]);
                } else {
#pragma unroll
                    for (int r = 0; r < 4; ++r) {
                        float vld = (jbase + r < Nn) ? 1.f : 0.f;
                        p[r] = fexp2(S[it][jt][r]) * vld;
                    }
                }
                lacc[it][jt] += (p[0] + p[1]) + (p[2] + p[3]);
                unsigned u = (unsigned)__builtin_amdgcn_cvt_pk_fp8_f32(p[0], p[1], 0, false);
                u = (unsigned)__builtin_amdgcn_cvt_pk_fp8_f32(p[2], p[3], (int)u, true);
                expS8[irow * STR4 + (jbase >> 2)] = u;
            }
        }
#pragma unroll
        for (int jt = 0; jt < 2; ++jt)
#pragma unroll
            for (int kc = 0; kc < 2; ++kc)
                Kc[jt][kc] = Kn[jt][kc];
    }

    __syncthreads();
#pragma unroll
    for (int it = 0; it < 2; ++it)
        red16[ws * 4 + q][it * 16 + i16] = lacc[it][0] + lacc[it][1];
    __syncthreads();
    if (tid < 32) {
        float s = 0.f;
#pragma unroll
        for (int t = 0; t < 16; ++t) s += red16[t][tid];
        int gi = ib * 32 + tid;
        linv[tid] = (gi < Nn) ? 1.f / s : 0.f;
    }
    __syncthreads();

    float* prow = colsum_part + (size_t)(bh * NIB32 + ib) * JP;
    for (int grp = tid; grp < 288; grp += 256) {
        float a0 = 0.f, a1 = 0.f, a2 = 0.f, a3 = 0.f;
#pragma unroll 8
        for (int i = 0; i < 32; ++i) {
            unsigned v = expS8[i * STR4 + grp];
            float li = linv[i];
            a0 += __builtin_amdgcn_cvt_f32_fp8(v, 0) * li;
            a1 += __builtin_amdgcn_cvt_f32_fp8(v, 1) * li;
            a2 += __builtin_amdgcn_cvt_f32_fp8(v, 2) * li;
            a3 += __builtin_amdgcn_cvt_f32_fp8(v, 3) * li;
        }
        float4 o = {a0, a1, a2, a3};
        *(float4*)&prow[grp * 4] = o;
    }
}

// ---------------------------------------------------------------------------
// 396-way partial reduction over 128 blocks -> UCB scores.
__global__ __launch_bounds__(256)
void colsum_reduce(const float* __restrict__ colsum_part,
                   const float* __restrict__ ucb_score,
                   const int* __restrict__ counter_p,
                   float* __restrict__ scoreF)
{
    const int b = blockIdx.x, jc = blockIdx.y;   // grid (4, 32)
    const int tid = threadIdx.x;
    const int j32 = tid & 31, grp = tid >> 5;    // 8 row-groups x 32 tokens
    const int t = jc * 32 + j32 + 1;             // token 1..1024
    __shared__ float red[8][32];

    const float* pb = colsum_part + (size_t)b * NPART * JP + t;
    float a0 = 0.f, a1 = 0.f;
    int r = grp;
    for (; r + 8 < NPART; r += 16) {
        a0 += pb[(size_t)r * JP];
        a1 += pb[(size_t)(r + 8) * JP];
    }
    for (; r < NPART; r += 8) a0 += pb[(size_t)r * JP];
    red[grp][j32] = a0 + a1;
    __syncthreads();

    if (tid < 32) {
        float cs = 0.f;
#pragma unroll
        for (int g = 0; g < 8; ++g) cs += red[g][tid];
        int tt = jc * 32 + tid + 1;
        float lc = logf((float)(*counter_p) + 1.0f);
        float s = cs * (1.0f / (float)Nn);
#pragma unroll
        for (int h = 0; h < Hh; ++h)
            s += sqrtf(lc / (ucb_score[h * Nn + tt] + 1e-6f));
        s *= (1.0f / (float)Hh);
        scoreF[b * NSCORE + tt - 1] = s;
    }
}

// ---------------------------------------------------------------------------
// Exact top-256 via counting select.  ~6 barriers total vs 55 (bitonic).
// Self-zeroes keepP/cnt_b rows (ws is poison!).
__global__ __launch_bounds__(1024)
void ucb_topk(const float* __restrict__ scoreF,
              float* __restrict__ keepP, float* __restrict__ cnt_b)
{
    const int b = blockIdx.x;
    const int tid = threadIdx.x;
    const int w = tid >> 6, ln = tid & 63;
    __shared__ int hist[8192];                   // 32 KB
    __shared__ int wtot[16];
    __shared__ unsigned ckey[1024];
    __shared__ int cidx[1024];
    __shared__ int s_tb, s_rem, ccount;

    for (int tpos = tid; tpos < JP; tpos += 1024) {
        keepP[b * JP + tpos] = 0.f;
        cnt_b[b * JP + tpos] = 0.f;
    }

    const unsigned key = __float_as_uint(scoreF[b * NSCORE + tid]);

    for (int tpos = tid; tpos < 8192; tpos += 1024) hist[tpos] = 0;
    if (tid == 0) ccount = 0;
    __syncthreads();
    atomicAdd(&hist[key >> 18], 1);
    __syncthreads();

    int part = 0;
#pragma unroll
    for (int q2 = 0; q2 < 8; ++q2) part += hist[tid * 8 + q2];
    int v = part;
#pragma unroll
    for (int off = 1; off < 64; off <<= 1) {
        int tv = __shfl_down(v, off);
        if (ln + off < 64) v += tv;
    }
    if (ln == 0) wtot[w] = v;
    __syncthreads();
    int woff = 0;
    for (int w2 = w + 1; w2 < 16; ++w2) woff += wtot[w2];
    int cum_above = v + woff - part;
    for (int q2 = 7; q2 >= 0; --q2) {
        int c = hist[tid * 8 + q2];
        if (cum_above < KSEL && cum_above + c >= KSEL) {
            s_tb = tid * 8 + q2;
            s_rem = KSEL - cum_above;
        }
        cum_above += c;
    }
    __syncthreads();

    const int tb = s_tb, rem = s_rem;
    const int mybin = (int)(key >> 18);
    bool sel = mybin > tb;
    if (mybin == tb) {
        int p = atomicAdd(&ccount, 1);
        ckey[p] = key; cidx[p] = tid;
    }
    __syncthreads();
    if (mybin == tb) {
        int rr = 0;
        const int cc = ccount;
        for (int c = 0; c < cc; ++c) {
            unsigned kc2 = ckey[c]; int ic = cidx[c];
            if (kc2 > key || (kc2 == key && ic < tid)) ++rr;
        }
        sel = rr < rem;
    }
    if (sel) {
        int tok = tid + 1;
        keepP[b * JP + tok] = 1.f;
        cnt_b[b * JP + tok] = 1.0f / (float)Bb;
    }
    if (tid == 0) keepP[b * JP + 0] = 1.f;
}

// ---------------------------------------------------------------------------
// Pass B: masked renormalized context.  64-row i-blocks (it=4 ILP), grid
// 816 XCD-swizzled.  R7: register diet for occupancy — NO K/V double-
// buffer (K/V are L2-resident, TLP covers latency), NO ds4 (dsacc VALU),
// mask via QK C-init bias.  ~165 VGPR -> launch_bounds(256,3):
// 3 waves/SIMD vs 2 (R5 counters: stall-bound, MfmaUtil 13/VALU 39).
__global__ __launch_bounds__(256, 3)
void attn_ctx_mfma(const unsigned short* __restrict__ qB,
                   const unsigned short* __restrict__ kF,
                   const unsigned short* __restrict__ vF,
                   const float* __restrict__ keepP, const float* __restrict__ cnt_b,
                   unsigned short* __restrict__ ctxA, float* __restrict__ out2)
{
    __shared__ float keeps[JP];                   // 4,608 B
    __shared__ float red16[16][64];               // 4,096 B
    __shared__ float dinv[64];                    // 256 B
    __shared__ float redC[64][66];                // 16,896 B

    const int blk = blockIdx.x;                 // 816 = 8 * 102
    const int x8 = blk & 7, g = blk >> 3;
    const int bh = x8 * 6 + (g % 6);
    const int ib = g / 6;
    const int b = bh / Hh, h = bh % Hh;
    const int tid = threadIdx.x;
    const int ws = tid >> 6;
    const int ln = tid & 63;
    const int i16 = ln & 15, q = ln >> 4;

    // fused score_delta write (out2[t] = sum_b cnt_b[b][t%Nn])
    {
        int t = blk * 256 + tid;
        if (t < Hh * Nn) {
            int n = t % Nn;
            out2[t] = cnt_b[0 * JP + n] + cnt_b[1 * JP + n]
                    + cnt_b[2 * JP + n] + cnt_b[3 * JP + n];
        }
    }

    for (int t = tid; t < JP; t += 256) keeps[t] = keepP[b * JP + t];

    const unsigned short* kBase = kF + (size_t)bh * JT16 * 1024;
    const unsigned short* vBase = vF + (size_t)bh * JT32 * 2048;

    short8 Qf[4][2];
#pragma unroll
    for (int it = 0; it < 4; ++it)
#pragma unroll
        for (int kc = 0; kc < 2; ++kc)
            Qf[it][kc] = *(const short8*)&qB[(((size_t)bh * IT_TILES + ib * 4 + it) * 2 + kc) * 512 + ln * 8];

    __syncthreads();                     // keeps staged

    float keepi[4];
#pragma unroll
    for (int it = 0; it < 4; ++it)
        keepi[it] = keeps[(ib * 4 + it) * 16 + i16];

    floatx4 ctxacc[4][4];
#pragma unroll
    for (int it = 0; it < 4; ++it)
#pragma unroll
        for (int dt = 0; dt < 4; ++dt)
            ctxacc[it][dt] = (floatx4){0.f, 0.f, 0.f, 0.f};
    float dsacc[4] = {0.f, 0.f, 0.f, 0.f};

    for (int sw = 0; sw < NSW; ++sw) {
        // direct (non-double-buffered) K/V loads: L2-hit latency covered
        // by 12 waves/CU TLP
        short8 Kc[2][2], Vc8[4];
#pragma unroll
        for (int jt = 0; jt < 2; ++jt)
#pragma unroll
            for (int kc = 0; kc < 2; ++kc)
                Kc[jt][kc] = *(const short8*)&kBase[(((size_t)(sw * 8 + ws * 2 + jt) * 2 + kc) * 64 + ln) * 8];
#pragma unroll
        for (int dt = 0; dt < 4; ++dt)
            Vc8[dt] = *(const short8*)&vBase[((((size_t)sw * 4 + ws) * 4 + dt) * 64 + ln) * 8];

        // per-sweep mask biases (log2 domain): kept rows use validity,
        // non-kept rows use keep-mask (keeps==0 beyond Nn covers padding)
        float biasK[2][4], biasN[2][4];
#pragma unroll
        for (int jt = 0; jt < 2; ++jt)
#pragma unroll
            for (int r = 0; r < 4; ++r) {
                int jj = sw * 128 + ws * 32 + jt * 16 + q * 4 + r;
                biasK[jt][r] = (jj < Nn) ? 0.f : MBIAS;
                biasN[jt][r] = (keeps[jj] - 1.f) * 30000.f;
            }

#pragma unroll
        for (int it = 0; it < 4; ++it) {
            bool rk = keepi[it] > 0.5f;
            floatx4 S[2];
#pragma unroll
            for (int jt = 0; jt < 2; ++jt)
#pragma unroll
                for (int r = 0; r < 4; ++r)
                    S[jt][r] = rk ? biasK[jt][r] : biasN[jt][r];
#pragma unroll
            for (int jt = 0; jt < 2; ++jt)
#pragma unroll
                for (int kc = 0; kc < 2; ++kc)
                    S[jt] = __builtin_amdgcn_mfma_f32_16x16x32_bf16(Kc[jt][kc], Qf[it][kc], S[jt], 0, 0, 0);

            float p0[4], p1[4];
#pragma unroll
            for (int r = 0; r < 4; ++r) {
                p0[r] = fexp2(S[0][r]);
                p1[r] = fexp2(S[1][r]);
            }
            dsacc[it] += ((p0[0] + p0[1]) + (p0[2] + p0[3]))
                       + ((p1[0] + p1[1]) + (p1[2] + p1[3]));
            unsigned Au = pkbf(p0[0], p0[1]);
            unsigned Bu = pkbf(p0[2], p0[3]);
            unsigned Cu = pkbf(p1[0], p1[1]);
            unsigned Du = pkbf(p1[2], p1[3]);
            asm("v_permlane32_swap_b32 %0, %1" : "+v"(Au), "+v"(Cu));
            asm("v_permlane32_swap_b32 %0, %1" : "+v"(Bu), "+v"(Du));
            asm("v_permlane16_swap_b32 %0, %1" : "+v"(Au), "+v"(Cu));
            asm("v_permlane16_swap_b32 %0, %1" : "+v"(Bu), "+v"(Du));
            short8 Wf = __builtin_bit_cast(short8, (uintx4){Au, Bu, Cu, Du});
#pragma unroll
            for (int dt = 0; dt < 4; ++dt)
                ctxacc[it][dt] = __builtin_amdgcn_mfma_f32_16x16x32_bf16(
                    Wf, Vc8[dt], ctxacc[it][dt], 0, 0, 0);
        }
    }

    // denominator reduce
    __syncthreads();
#pragma unroll
    for (int it = 0; it < 4; ++it) red16[ws * 4 + q][it * 16 + i16] = dsacc[it];
    __syncthreads();
    if (tid < 64) {
        float s = 0.f;
#pragma unroll
        for (int t = 0; t < 16; ++t) s += red16[t][tid];
        dinv[tid] = 1.f / (s + 1e-8f);
    }
    // cross-wave ctx reduce into redC
    for (int w = 0; w < 4; ++w) {
        __syncthreads();
        if (ws == w) {
#pragma unroll
            for (int it = 0; it < 4; ++it)
#pragma unroll
                for (int dt = 0; dt < 4; ++dt)
#pragma unroll
                    for (int r = 0; r < 4; ++r) {
                        int i = it * 16 + q * 4 + r;
                        int d = dt * 16 + i16;
                        float v = ctxacc[it][dt][r];
                        redC[i][d] = (w == 0) ? v : (redC[i][d] + v);
                    }
        }
    }
    __syncthreads();
    // write ctxA in A-fragment order: m = b*Nn+gi, k = h*64+d
#pragma unroll
    for (int rep = 0; rep < 2; ++rep) {
        int s2 = tid + rep * 256;          // < 512 : i(6b) x dc(3b)
        int i = s2 >> 3, dc = s2 & 7;
        int gi = ib * 64 + i;
        if (gi < Nn) {
            int m = b * Nn + gi;
            float dv = dinv[i];
            const float* src = &redC[i][dc * 8];
            uint4 pk;
            pk.x = (unsigned)f2bf(src[0] * dv) | ((unsigned)f2bf(src[1] * dv) << 16);
            pk.y = (unsigned)f2bf(src[2] * dv) | ((unsigned)f2bf(src[3] * dv) << 16);
            pk.z = (unsigned)f2bf(src[4] * dv) | ((unsigned)f2bf(src[5] * dv) << 16);
            pk.w = (unsigned)f2bf(src[6] * dv) | ((unsigned)f2bf(src[7] * dv) << 16);
            int kc2 = h * 2 + (dc >> 2);
            int q2 = dc & 3;
            size_t idx = (((size_t)(kc2 * MT16 + (m >> 4))) * 64 + q2 * 16 + (m & 15)) * 8;
            *(uint4*)&ctxA[idx] = pk;
        }
    }
}

// ---------------------------------------------------------------------------
extern "C" void kernel_launch(void* const* d_in, const int* in_sizes, int n_in,
                              void* d_out, int out_size, void* d_ws, size_t ws_size,
                              hipStream_t stream) {
    const float* x     = (const float*)d_in[0];
    const float* ucb   = (const float*)d_in[1];
    const float* Wqkv  = (const float*)d_in[2];
    const float* Wproj = (const float*)d_in[3];
    const float* bproj = (const float*)d_in[4];
    const int*   counter = (const int*)d_in[5];

    unsigned short* qB = (unsigned short*)d_ws;      // 3,342,336 sh
    unsigned short* kF = qB + 3342336;               // 3,538,944 sh
    unsigned short* vF = kF + 3538944;               // 3,538,944 sh
    float* keepP    = (float*)(vF + 3538944);        // 4608 f
    float* cnt_b    = keepP + 4608;                  // 4608 f
    unsigned short* ctxA = (unsigned short*)(cnt_b + 4608);  // 3,244,032 sh
    unsigned short* xA   = ctxA + 3244032;           // 3,244,032 sh
    unsigned short* WB   = xA + 3244032;             // 1,769,472 sh
    unsigned short* WpB  = WB + 1769472;             // 589,824 sh
    float* colsum_part = (float*)(WpB + 589824);     // 1,824,768 f
    float* scoreF = colsum_part + 1824768;           // 4,096 f

    float* out  = (float*)d_out;                     // [B,N,C]
    float* out2 = out + 3148800;                     // [H,N]

    cast_all<<<dim3(CAST_X_BLK + CAST_WQKV_BLK + CAST_WPROJ_BLK), dim3(256), 0, stream>>>(
        x, Wqkv, Wproj, xA, WB, WpB);
    gemm_mfma<4, 0><<<dim3(33, 18), dim3(256), 0, stream>>>(
        xA, WB, 144, qB, kF, vF, nullptr, nullptr);
    attn_colsum_mfma<<<dim3(8 * 198), dim3(256), 0, stream>>>(qB, kF, colsum_part);
    colsum_reduce<<<dim3(Bb, 32), dim3(256), 0, stream>>>(colsum_part, ucb, counter, scoreF);
    ucb_topk<<<dim3(Bb), dim3(1024), 0, stream>>>(scoreF, keepP, cnt_b);
    attn_ctx_mfma<<<dim3(8 * 102), dim3(256), 0, stream>>>(qB, kF, vF, keepP, cnt_b, ctxA, out2);
    gemm_mfma<2, 1><<<dim3(33, 12), dim3(256), 0, stream>>>(
        ctxA, WpB, 48, nullptr, nullptr, nullptr, out, bproj);
}

// Round 8
// 193.103 us; speedup vs baseline: 1.1083x; 1.1083x over previous
//
#include <hip/hip_runtime.h>
#include <hip/hip_bf16.h>
#include <math.h>

// Problem constants
#define Bb 4
#define Nn 1025
#define Cc 768
#define Hh 12
#define BH (Bb*Hh)          // 48
#define M_ROWS 4100
#define KSEL 256            // int(1024*0.25)
#define JP 1152             // padded j (9 sweeps x 128)
#define IT_TILES 68         // qB i-tiles of 16 (i < 1088)
#define NIB32 33            // colsum i-blocks of 32
#define NSW 9               // j-sweeps of 128
#define MT16 264            // padded M tiles of 16 (4224 rows)
#define KC24 24             // 768/32 k-chunks
#define JT16 72             // j 16-tiles (1152/16)
#define JT32 36             // j 32-tiles (1152/32) for V K=32 B-frags
#define STR4 292            // expS8 row stride in u32 (288 used + 4 pad)
#define NPART 396           // partial rows per batch (12 h * 33 ib)
#define NSCORE 1024         // patch tokens scored per batch
#define QSCALE 0.18033688011112042f   // 0.125 * log2(e): S is in log2 domain
#define MBIAS -30000.0f     // log2-domain mask: exp2(-30000+S) == 0.0 exactly
#define OSTR 136            // ldsO row stride in shorts (272B, 16B-aligned rows)

// cast_all region sizes (in 256-thread blocks)
#define CAST_X_BLK 1584     // 405,504 slots
#define CAST_WQKV_BLK 864   // 221,184 slots
#define CAST_WPROJ_BLK 288  // 73,728 slots

typedef __attribute__((ext_vector_type(8))) short short8;
typedef __attribute__((ext_vector_type(4))) float floatx4;
typedef __attribute__((ext_vector_type(4))) unsigned uintx4;

static __device__ inline unsigned short f2bf(float v) {       // RNE
    __hip_bfloat16 b = __float2bfloat16(v);
    return *reinterpret_cast<unsigned short*>(&b);
}
static __device__ inline float fexp2(float x) {
    return __builtin_amdgcn_exp2f(x);
}
// pack two f32 -> bf16x2 u32 by truncation (lo = first arg)
static __device__ inline unsigned pkbf(float lo, float hi) {
    union { float f; unsigned u; } a, b;
    a.f = lo; b.f = hi;
    return (a.u >> 16) | (b.u & 0xffff0000u);
}

// async global->LDS, 16B per lane; lds dest must be wave-uniform base
static __device__ inline void async16(const unsigned short* g, unsigned short* l) {
    __builtin_amdgcn_global_load_lds(
        (const __attribute__((address_space(1))) unsigned int*)g,
        (__attribute__((address_space(3))) unsigned int*)l, 16, 0, 0);
}

// ---------------------------------------------------------------------------
// Fused input casts: x -> xA (A-frag), Wqkv -> WB (B-frag), Wproj -> WpB.
__global__ __launch_bounds__(256)
void cast_all(const float* __restrict__ x, const float* __restrict__ Wqkv,
              const float* __restrict__ Wproj,
              unsigned short* __restrict__ xA, unsigned short* __restrict__ WB,
              unsigned short* __restrict__ WpB)
{
    int blk = blockIdx.x;
    int tid = threadIdx.x;
    if (blk < CAST_X_BLK) {
        int s = blk * 256 + tid;                    // < 405504
        int ml = s & 15, q = (s >> 4) & 3;
        int t2 = s >> 6;
        int mt = t2 % MT16, kc = t2 / MT16;
        int m = mt * 16 + ml, k = kc * 32 + q * 8;
        uint4 pk = {0u, 0u, 0u, 0u};
        if (m < M_ROWS) {
            float4 a = *(const float4*)&x[(size_t)m * 768 + k];
            float4 b2 = *(const float4*)&x[(size_t)m * 768 + k + 4];
            pk.x = (unsigned)f2bf(a.x)  | ((unsigned)f2bf(a.y)  << 16);
            pk.y = (unsigned)f2bf(a.z)  | ((unsigned)f2bf(a.w)  << 16);
            pk.z = (unsigned)f2bf(b2.x) | ((unsigned)f2bf(b2.y) << 16);
            pk.w = (unsigned)f2bf(b2.z) | ((unsigned)f2bf(b2.w) << 16);
        }
        *(uint4*)&xA[(size_t)s * 8] = pk;
        return;
    }
    const float* W;
    unsigned short* WO;
    int N, NT, s;
    if (blk < CAST_X_BLK + CAST_WQKV_BLK) {
        W = Wqkv; WO = WB; N = 2304; NT = 144;
        s = (blk - CAST_X_BLK) * 256 + tid;
    } else {
        W = Wproj; WO = WpB; N = 768; NT = 48;
        s = (blk - CAST_X_BLK - CAST_WQKV_BLK) * 256 + tid;
    }
    int nl = s & 15, q = (s >> 4) & 3;
    int t2 = s >> 6;
    int nt = t2 % NT, kc = t2 / NT;
    int n = nt * 16 + nl, k = kc * 32 + q * 8;
    unsigned hv[8];
#pragma unroll
    for (int e = 0; e < 8; ++e)
        hv[e] = f2bf(W[(size_t)(k + e) * N + n]);
    uint4 pk;
    pk.x = hv[0] | (hv[1] << 16);
    pk.y = hv[2] | (hv[3] << 16);
    pk.z = hv[4] | (hv[5] << 16);
    pk.w = hv[6] | (hv[7] << 16);
    *(uint4*)&WO[(size_t)s * 8] = pk;
}

// ---------------------------------------------------------------------------
// MFMA bf16 GEMM, 128x(NT*32) tile, 4 waves x (4xNT of 16x16x32), BK=32.
// MODE 0 (R8): epilogue stages the 128x128 tile in LDS (aliased over the
// dead staging buffers) then emits COALESCED uint4 stores — the old path
// was 64 scattered scalar u16 stores/thread (~16x L2 write amplification).
// s (q/k/v region) is uniform per block (boundaries 768/1536 are multiples
// of 128).  q/k: vectors of 8 consecutive d.  v: vectors of 8 consecutive
// n per 8-aligned n-group (elem=n&7 in the B-frag); batch-boundary groups
// fall back to scalar stores of valid elements only (no cross-block clobber).
template<int NT, int MODE>
__global__ __launch_bounds__(256, 3)
void gemm_mfma(const unsigned short* __restrict__ Af,
               const unsigned short* __restrict__ Bf,
               int Nt16,
               unsigned short* __restrict__ qB, unsigned short* __restrict__ kF,
               unsigned short* __restrict__ vF,
               float* __restrict__ outp, const float* __restrict__ bias)
{
    __shared__ __align__(16) unsigned short smemU[(MODE == 0) ? (128 * OSTR) : (4096 + NT * 1024)];
    unsigned short* ldsA = smemU;
    unsigned short* ldsB = smemU + 4096;
    const int tid = threadIdx.x;
    const int ln = tid & 63, w = tid >> 6;
    const int wm = w >> 1, wn = w & 1;
    const int mb = blockIdx.x, nb = blockIdx.y;

    floatx4 acc[4][NT];
#pragma unroll
    for (int mt = 0; mt < 4; ++mt)
#pragma unroll
        for (int nt = 0; nt < NT; ++nt)
            acc[mt][nt] = (floatx4){0.f, 0.f, 0.f, 0.f};

    for (int kc = 0; kc < KC24; ++kc) {
        const unsigned short* gA = Af + ((size_t)(kc * MT16 + mb * 8)) * 512;
        const unsigned short* gB = Bf + ((size_t)(kc * Nt16 + nb * (NT * 2))) * 512;
        async16(gA + (size_t)(w * 128 + ln) * 8,      &ldsA[w * 1024]);
        async16(gA + (size_t)(w * 128 + 64 + ln) * 8, &ldsA[w * 1024 + 512]);
        if (NT == 4) {
            async16(gB + (size_t)(w * 128 + ln) * 8,      &ldsB[w * 1024]);
            async16(gB + (size_t)(w * 128 + 64 + ln) * 8, &ldsB[w * 1024 + 512]);
        } else {
            async16(gB + (size_t)(w * 64 + ln) * 8, &ldsB[w * 512]);
        }
        __syncthreads();

        short8 Am[4], Bn[NT];
#pragma unroll
        for (int mt = 0; mt < 4; ++mt)
            Am[mt] = *(const short8*)&ldsA[((wm * 4 + mt) * 64 + ln) * 8];
#pragma unroll
        for (int nt = 0; nt < NT; ++nt)
            Bn[nt] = *(const short8*)&ldsB[((wn * NT + nt) * 64 + ln) * 8];
#pragma unroll
        for (int mt = 0; mt < 4; ++mt)
#pragma unroll
            for (int nt = 0; nt < NT; ++nt)
                acc[mt][nt] = __builtin_amdgcn_mfma_f32_16x16x32_bf16(
                    Am[mt], Bn[nt], acc[mt][nt], 0, 0, 0);
        __syncthreads();
    }

    const int q = ln >> 4, l15 = ln & 15;
    if (MODE == 1) {
#pragma unroll
        for (int nt = 0; nt < NT; ++nt) {
            int gn = nb * (NT * 32) + wn * (NT * 16) + nt * 16 + l15;
            float bv = bias[gn];
#pragma unroll
            for (int mt = 0; mt < 4; ++mt) {
                int gmb = mb * 128 + wm * 64 + mt * 16 + q * 4;
#pragma unroll
                for (int r = 0; r < 4; ++r) {
                    int gm = gmb + r;
                    if (gm < M_ROWS)
                        outp[(size_t)gm * 768 + gn] = acc[mt][nt][r] + bv;
                }
            }
        }
    } else {
        // ---- stage tile to LDS as bf16 (scale folded; s uniform per block)
        const int s = (nb >= 12) ? 2 : (nb >= 6 ? 1 : 0);
        const float scl = (s == 0) ? QSCALE : 1.f;
        unsigned short* ldsO = smemU;
#pragma unroll
        for (int mt = 0; mt < 4; ++mt)
#pragma unroll
            for (int nt = 0; nt < NT; ++nt)
#pragma unroll
                for (int r = 0; r < 4; ++r) {
                    int row = wm * 64 + mt * 16 + q * 4 + r;
                    int col = wn * 64 + nt * 16 + l15;
                    ldsO[row * OSTR + col] = f2bf(acc[mt][nt][r] * scl);
                }
        __syncthreads();

        const int gm0 = mb * 128;
        if (s < 2) {
            // vectors of 8 consecutive d; lanes sweep rows -> coalesced
            const int c = tid >> 4;                   // d-block 0..15
            const int gn = nb * 128 + c * 8;
            const int rr = gn - s * Cc;
            const int h = rr >> 6, d0 = rr & 63;
#pragma unroll
            for (int rt = 0; rt < 8; ++rt) {
                int row = rt * 16 + (tid & 15);
                int gm = gm0 + row;
                if (gm >= M_ROWS) continue;
                int b = gm / Nn;
                int n = gm - b * Nn;
                int bh = b * Hh + h;
                uint4 v = *(const uint4*)&ldsO[row * OSTR + c * 8];
                if (s == 0) {
                    int idx = (((bh * IT_TILES + (n >> 4)) * 2 + (d0 >> 5)) * 512)
                              + ((((d0 & 31) >> 3) * 16 + (n & 15)) * 8);
                    *(uint4*)&qB[idx] = v;
                } else {
                    size_t idx = ((((size_t)bh * JT16 + (n >> 4)) * 2 + (d0 >> 5)) * 64
                                  + ((d0 >> 3) & 3) * 16 + (n & 15)) * 8;
                    *(uint4*)&kF[idx] = v;
                }
            }
        } else {
            // v region: vectors of 8 consecutive n (elem = n&7 in B-frag)
            int b0 = gm0 / Nn;
#pragma unroll 2
            for (int bi = 0; bi < 2; ++bi) {
                int b = b0 + bi;
                if (b >= Bb) break;
                int n0 = gm0 - b * Nn;                 // n of local row 0 (may be <0)
                int nlo = n0 < 0 ? 0 : n0;
                int nhi = n0 + 127;
                if (nhi > Nn - 1) nhi = Nn - 1;
                int nmx = M_ROWS - b * Nn - 1;
                if (nhi > nmx) nhi = nmx;
                if (nhi < nlo) continue;
                int ngl = nlo >> 3;
                int ngc = (nhi >> 3) - ngl + 1;
                for (int task = tid; task < 128 * ngc; task += 256) {
                    int dd = task & 127, ngi = task >> 7;
                    int nbase = (ngl + ngi) * 8;
                    int gn = nb * 128 + dd;
                    int rr = gn - 2 * Cc;
                    int h = rr >> 6, d = rr & 63;
                    int bh = b * Hh + h;
                    size_t idx = ((((size_t)bh * JT32 + (nbase >> 5)) * 4 + (d >> 4)) * 64
                                  + ((nbase >> 3) & 3) * 16 + (d & 15)) * 8;
                    if (nbase >= nlo && nbase + 7 <= nhi) {
                        int rowb = nbase - n0;
                        unsigned short vv[8];
#pragma unroll
                        for (int e = 0; e < 8; ++e)
                            vv[e] = ldsO[(rowb + e) * OSTR + dd];
                        *(uint4*)&vF[idx] = *(const uint4*)vv;
                    } else {
                        for (int e = 0; e < 8; ++e) {
                            int n = nbase + e;
                            if (n < nlo || n > nhi) continue;
                            vF[idx + e] = ldsO[(n - n0) * OSTR + dd];
                        }
                    }
                }
            }
        }
    }
}

// ---------------------------------------------------------------------------
// Pass A: SINGLE-QK colsum (expS as fp8 e4m3 in LDS, 4 blocks/CU).
// Valid-mask multiply applied only in the last sweep (identity for sw<8).
__global__ __launch_bounds__(256, 4)
void attn_colsum_mfma(const unsigned short* __restrict__ qB,
                      const unsigned short* __restrict__ kF,
                      float* __restrict__ colsum_part)
{
    __shared__ unsigned int expS8[32 * STR4];     // 37,376 B  fp8 [i][j/4]
    __shared__ float red16[16][32];               // 2,048 B
    __shared__ float linv[32];

    const int blk = blockIdx.x;                 // 1584 = 8 * 198
    const int x8 = blk & 7, g = blk >> 3;
    const int bh = x8 * 6 + (g % 6);
    const int ib = g / 6;                        // 0..32
    const int tid = threadIdx.x;
    const int ws = tid >> 6;
    const int ln = tid & 63;
    const int i16 = ln & 15, q = ln >> 4;

    const unsigned short* kBase = kF + (size_t)bh * JT16 * 1024;

    short8 Qf[2][2];
#pragma unroll
    for (int it = 0; it < 2; ++it)
#pragma unroll
        for (int kc = 0; kc < 2; ++kc)
            Qf[it][kc] = *(const short8*)&qB[(((size_t)bh * IT_TILES + ib * 2 + it) * 2 + kc) * 512 + ln * 8];

    float lacc[2][2] = {{0.f, 0.f}, {0.f, 0.f}};

    short8 Kc[2][2], Kn[2][2];
#pragma unroll
    for (int jt = 0; jt < 2; ++jt)
#pragma unroll
        for (int kc = 0; kc < 2; ++kc)
            Kc[jt][kc] = *(const short8*)&kBase[(((ws * 2 + jt) * 2 + kc) * 64 + ln) * 8];

    for (int sw = 0; sw < NSW; ++sw) {
        if (sw + 1 < NSW) {
#pragma unroll
            for (int jt = 0; jt < 2; ++jt)
#pragma unroll
                for (int kc = 0; kc < 2; ++kc)
                    Kn[jt][kc] = *(const short8*)&kBase[((((sw + 1) * 8 + ws * 2 + jt) * 2 + kc) * 64 + ln) * 8];
        }

        floatx4 S[2][2];
#pragma unroll
        for (int it = 0; it < 2; ++it)
#pragma unroll
            for (int jt = 0; jt < 2; ++jt) {
                S[it][jt] = (floatx4){0.f, 0.f, 0.f, 0.f};
#pragma unroll
                for (int kc = 0; kc < 2; ++kc)
                    S[it][jt] = __builtin_amdgcn_mfma_f32_16x16x32_bf16(Kc[jt][kc], Qf[it][kc], S[it][jt], 0, 0, 0);
            }

        const int jbase0 = sw * 128 + ws * 32 + q * 4;
#pragma unroll
        for (int it = 0; it < 2; ++it) {
            const int irow = it * 16 + i16;
#pragma unroll
            for (int jt = 0; jt < 2; ++jt) {
                int jbase = jbase0 + jt * 16;
                float p[4];
                if (sw < NSW - 1) {
#pragma unroll
                    for (int r = 0; r < 4; ++r)
                        p[r] = fexp2(S[it][jt][r]);
                } else {
#pragma unroll
                    for (int r = 0; r < 4; ++r) {
                        float vld = (jbase + r < Nn) ? 1.f : 0.f;
                        p[r] = fexp2(S[it][jt][r]) * vld;
                    }
                }
                lacc[it][jt] += (p[0] + p[1]) + (p[2] + p[3]);
                unsigned u = (unsigned)__builtin_amdgcn_cvt_pk_fp8_f32(p[0], p[1], 0, false);
                u = (unsigned)__builtin_amdgcn_cvt_pk_fp8_f32(p[2], p[3], (int)u, true);
                expS8[irow * STR4 + (jbase >> 2)] = u;
            }
        }
#pragma unroll
        for (int jt = 0; jt < 2; ++jt)
#pragma unroll
            for (int kc = 0; kc < 2; ++kc)
                Kc[jt][kc] = Kn[jt][kc];
    }

    __syncthreads();
#pragma unroll
    for (int it = 0; it < 2; ++it)
        red16[ws * 4 + q][it * 16 + i16] = lacc[it][0] + lacc[it][1];
    __syncthreads();
    if (tid < 32) {
        float s = 0.f;
#pragma unroll
        for (int t = 0; t < 16; ++t) s += red16[t][tid];
        int gi = ib * 32 + tid;
        linv[tid] = (gi < Nn) ? 1.f / s : 0.f;
    }
    __syncthreads();

    float* prow = colsum_part + (size_t)(bh * NIB32 + ib) * JP;
    for (int grp = tid; grp < 288; grp += 256) {
        float a0 = 0.f, a1 = 0.f, a2 = 0.f, a3 = 0.f;
#pragma unroll 8
        for (int i = 0; i < 32; ++i) {
            unsigned v = expS8[i * STR4 + grp];
            float li = linv[i];
            a0 += __builtin_amdgcn_cvt_f32_fp8(v, 0) * li;
            a1 += __builtin_amdgcn_cvt_f32_fp8(v, 1) * li;
            a2 += __builtin_amdgcn_cvt_f32_fp8(v, 2) * li;
            a3 += __builtin_amdgcn_cvt_f32_fp8(v, 3) * li;
        }
        float4 o = {a0, a1, a2, a3};
        *(float4*)&prow[grp * 4] = o;
    }
}

// ---------------------------------------------------------------------------
// 396-way partial reduction over 128 blocks -> UCB scores.
__global__ __launch_bounds__(256)
void colsum_reduce(const float* __restrict__ colsum_part,
                   const float* __restrict__ ucb_score,
                   const int* __restrict__ counter_p,
                   float* __restrict__ scoreF)
{
    const int b = blockIdx.x, jc = blockIdx.y;   // grid (4, 32)
    const int tid = threadIdx.x;
    const int j32 = tid & 31, grp = tid >> 5;    // 8 row-groups x 32 tokens
    const int t = jc * 32 + j32 + 1;             // token 1..1024
    __shared__ float red[8][32];

    const float* pb = colsum_part + (size_t)b * NPART * JP + t;
    float a0 = 0.f, a1 = 0.f;
    int r = grp;
    for (; r + 8 < NPART; r += 16) {
        a0 += pb[(size_t)r * JP];
        a1 += pb[(size_t)(r + 8) * JP];
    }
    for (; r < NPART; r += 8) a0 += pb[(size_t)r * JP];
    red[grp][j32] = a0 + a1;
    __syncthreads();

    if (tid < 32) {
        float cs = 0.f;
#pragma unroll
        for (int g = 0; g < 8; ++g) cs += red[g][tid];
        int tt = jc * 32 + tid + 1;
        float lc = logf((float)(*counter_p) + 1.0f);
        float s = cs * (1.0f / (float)Nn);
#pragma unroll
        for (int h = 0; h < Hh; ++h)
            s += sqrtf(lc / (ucb_score[h * Nn + tt] + 1e-6f));
        s *= (1.0f / (float)Hh);
        scoreF[b * NSCORE + tt - 1] = s;
    }
}

// ---------------------------------------------------------------------------
// Exact top-256 via counting select.  ~6 barriers total vs 55 (bitonic).
// Self-zeroes keepP/cnt_b rows (ws is poison!).
__global__ __launch_bounds__(1024)
void ucb_topk(const float* __restrict__ scoreF,
              float* __restrict__ keepP, float* __restrict__ cnt_b)
{
    const int b = blockIdx.x;
    const int tid = threadIdx.x;
    const int w = tid >> 6, ln = tid & 63;
    __shared__ int hist[8192];                   // 32 KB
    __shared__ int wtot[16];
    __shared__ unsigned ckey[1024];
    __shared__ int cidx[1024];
    __shared__ int s_tb, s_rem, ccount;

    for (int tpos = tid; tpos < JP; tpos += 1024) {
        keepP[b * JP + tpos] = 0.f;
        cnt_b[b * JP + tpos] = 0.f;
    }

    const unsigned key = __float_as_uint(scoreF[b * NSCORE + tid]);

    for (int tpos = tid; tpos < 8192; tpos += 1024) hist[tpos] = 0;
    if (tid == 0) ccount = 0;
    __syncthreads();
    atomicAdd(&hist[key >> 18], 1);
    __syncthreads();

    int part = 0;
#pragma unroll
    for (int q2 = 0; q2 < 8; ++q2) part += hist[tid * 8 + q2];
    int v = part;
#pragma unroll
    for (int off = 1; off < 64; off <<= 1) {
        int tv = __shfl_down(v, off);
        if (ln + off < 64) v += tv;
    }
    if (ln == 0) wtot[w] = v;
    __syncthreads();
    int woff = 0;
    for (int w2 = w + 1; w2 < 16; ++w2) woff += wtot[w2];
    int cum_above = v + woff - part;
    for (int q2 = 7; q2 >= 0; --q2) {
        int c = hist[tid * 8 + q2];
        if (cum_above < KSEL && cum_above + c >= KSEL) {
            s_tb = tid * 8 + q2;
            s_rem = KSEL - cum_above;
        }
        cum_above += c;
    }
    __syncthreads();

    const int tb = s_tb, rem = s_rem;
    const int mybin = (int)(key >> 18);
    bool sel = mybin > tb;
    if (mybin == tb) {
        int p = atomicAdd(&ccount, 1);
        ckey[p] = key; cidx[p] = tid;
    }
    __syncthreads();
    if (mybin == tb) {
        int rr = 0;
        const int cc = ccount;
        for (int c = 0; c < cc; ++c) {
            unsigned kc2 = ckey[c]; int ic = cidx[c];
            if (kc2 > key || (kc2 == key && ic < tid)) ++rr;
        }
        sel = rr < rem;
    }
    if (sel) {
        int tok = tid + 1;
        keepP[b * JP + tok] = 1.f;
        cnt_b[b * JP + tok] = 1.0f / (float)Bb;
    }
    if (tid == 0) keepP[b * JP + 0] = 1.f;
}

// ---------------------------------------------------------------------------
// Pass B: masked renormalized context — byte-exact R6 config (200.5 us):
// it=4 ILP, (256,2), register-dbuf K/V, mask via QK C-init bias, softmax
// denominator via ones-column MFMA.
__global__ __launch_bounds__(256, 2)
void attn_ctx_mfma(const unsigned short* __restrict__ qB,
                   const unsigned short* __restrict__ kF,
                   const unsigned short* __restrict__ vF,
                   const float* __restrict__ keepP, const float* __restrict__ cnt_b,
                   unsigned short* __restrict__ ctxA, float* __restrict__ out2)
{
    __shared__ float keeps[JP];                   // 4,608 B
    __shared__ float red16s[4][64];               // 1,024 B
    __shared__ float redC[64][66];                // 16,896 B

    const int blk = blockIdx.x;                 // 816 = 8 * 102
    const int x8 = blk & 7, g = blk >> 3;
    const int bh = x8 * 6 + (g % 6);
    const int ib = g / 6;
    const int b = bh / Hh, h = bh % Hh;
    const int tid = threadIdx.x;
    const int ws = tid >> 6;
    const int ln = tid & 63;
    const int i16 = ln & 15, q = ln >> 4;

    // fused score_delta write (out2[t] = sum_b cnt_b[b][t%Nn])
    {
        int t = blk * 256 + tid;
        if (t < Hh * Nn) {
            int n = t % Nn;
            out2[t] = cnt_b[0 * JP + n] + cnt_b[1 * JP + n]
                    + cnt_b[2 * JP + n] + cnt_b[3 * JP + n];
        }
    }

    for (int t = tid; t < JP; t += 256) keeps[t] = keepP[b * JP + t];

    const unsigned short* kBase = kF + (size_t)bh * JT16 * 1024;
    const unsigned short* vBase = vF + (size_t)bh * JT32 * 2048;

    short8 Qf[4][2];
#pragma unroll
    for (int it = 0; it < 4; ++it)
#pragma unroll
        for (int kc = 0; kc < 2; ++kc)
            Qf[it][kc] = *(const short8*)&qB[(((size_t)bh * IT_TILES + ib * 4 + it) * 2 + kc) * 512 + ln * 8];

    __syncthreads();                     // keeps staged

    float keepi[4];
#pragma unroll
    for (int it = 0; it < 4; ++it)
        keepi[it] = keeps[(ib * 4 + it) * 16 + i16];

    floatx4 ctxacc[4][4];
#pragma unroll
    for (int it = 0; it < 4; ++it)
#pragma unroll
        for (int dt = 0; dt < 4; ++dt)
            ctxacc[it][dt] = (floatx4){0.f, 0.f, 0.f, 0.f};
    floatx4 ds4[4];
#pragma unroll
    for (int it = 0; it < 4; ++it) ds4[it] = (floatx4){0.f, 0.f, 0.f, 0.f};

    const short obf = (short)0x3F80;              // bf16 1.0
    const short8 onesB = {obf, obf, obf, obf, obf, obf, obf, obf};

    short8 Kc[2][2], Kn[2][2];
    short8 Vc8[4], Vn8[4];
#pragma unroll
    for (int jt = 0; jt < 2; ++jt)
#pragma unroll
        for (int kc = 0; kc < 2; ++kc)
            Kc[jt][kc] = *(const short8*)&kBase[(((ws * 2 + jt) * 2 + kc) * 64 + ln) * 8];
#pragma unroll
    for (int dt = 0; dt < 4; ++dt)
        Vc8[dt] = *(const short8*)&vBase[(((size_t)ws * 4 + dt) * 64 + ln) * 8];

    for (int sw = 0; sw < NSW; ++sw) {
        if (sw + 1 < NSW) {
#pragma unroll
            for (int jt = 0; jt < 2; ++jt)
#pragma unroll
                for (int kc = 0; kc < 2; ++kc)
                    Kn[jt][kc] = *(const short8*)&kBase[((((sw + 1) * 8 + ws * 2 + jt) * 2 + kc) * 64 + ln) * 8];
#pragma unroll
            for (int dt = 0; dt < 4; ++dt)
                Vn8[dt] = *(const short8*)&vBase[((((size_t)(sw + 1) * 4 + ws) * 4 + dt) * 64 + ln) * 8];
        }

        // per-sweep mask biases (log2 domain): kept rows use validity,
        // non-kept rows use keep-mask (keeps==0 beyond Nn covers padding)
        float biasK[2][4], biasN[2][4];
#pragma unroll
        for (int jt = 0; jt < 2; ++jt)
#pragma unroll
            for (int r = 0; r < 4; ++r) {
                int jj = sw * 128 + ws * 32 + jt * 16 + q * 4 + r;
                biasK[jt][r] = (jj < Nn) ? 0.f : MBIAS;
                biasN[jt][r] = (keeps[jj] - 1.f) * 30000.f;
            }

#pragma unroll
        for (int it = 0; it < 4; ++it) {
            bool rk = keepi[it] > 0.5f;
            floatx4 S[2];
#pragma unroll
            for (int jt = 0; jt < 2; ++jt)
#pragma unroll
                for (int r = 0; r < 4; ++r)
                    S[jt][r] = rk ? biasK[jt][r] : biasN[jt][r];
#pragma unroll
            for (int jt = 0; jt < 2; ++jt)
#pragma unroll
                for (int kc = 0; kc < 2; ++kc)
                    S[jt] = __builtin_amdgcn_mfma_f32_16x16x32_bf16(Kc[jt][kc], Qf[it][kc], S[jt], 0, 0, 0);

            float p0[4], p1[4];
#pragma unroll
            for (int r = 0; r < 4; ++r) {
                p0[r] = fexp2(S[0][r]);
                p1[r] = fexp2(S[1][r]);
            }
            unsigned Au = pkbf(p0[0], p0[1]);
            unsigned Bu = pkbf(p0[2], p0[3]);
            unsigned Cu = pkbf(p1[0], p1[1]);
            unsigned Du = pkbf(p1[2], p1[3]);
            asm("v_permlane32_swap_b32 %0, %1" : "+v"(Au), "+v"(Cu));
            asm("v_permlane32_swap_b32 %0, %1" : "+v"(Bu), "+v"(Du));
            asm("v_permlane16_swap_b32 %0, %1" : "+v"(Au), "+v"(Cu));
            asm("v_permlane16_swap_b32 %0, %1" : "+v"(Bu), "+v"(Du));
            short8 Wf = __builtin_bit_cast(short8, (uintx4){Au, Bu, Cu, Du});
#pragma unroll
            for (int dt = 0; dt < 4; ++dt)
                ctxacc[it][dt] = __builtin_amdgcn_mfma_f32_16x16x32_bf16(
                    Wf, Vc8[dt], ctxacc[it][dt], 0, 0, 0);
            ds4[it] = __builtin_amdgcn_mfma_f32_16x16x32_bf16(
                Wf, onesB, ds4[it], 0, 0, 0);
        }

#pragma unroll
        for (int jt = 0; jt < 2; ++jt)
#pragma unroll
            for (int kc = 0; kc < 2; ++kc)
                Kc[jt][kc] = Kn[jt][kc];
#pragma unroll
        for (int dt = 0; dt < 4; ++dt)
            Vc8[dt] = Vn8[dt];
    }

    // denominator: ds4[it][r] (any col) = this wave's partial rowsum for
    // query row it*16 + q*4 + r.  Stage from col 0 lanes, sum over waves.
    __syncthreads();
    if (i16 == 0) {
#pragma unroll
        for (int it = 0; it < 4; ++it)
#pragma unroll
            for (int r = 0; r < 4; ++r)
                red16s[ws][it * 16 + q * 4 + r] = ds4[it][r];
    }
    // cross-wave ctx reduce into redC
    for (int w = 0; w < 4; ++w) {
        __syncthreads();
        if (ws == w) {
#pragma unroll
            for (int it = 0; it < 4; ++it)
#pragma unroll
                for (int dt = 0; dt < 4; ++dt)
#pragma unroll
                    for (int r = 0; r < 4; ++r) {
                        int i = it * 16 + q * 4 + r;
                        int d = dt * 16 + i16;
                        float v = ctxacc[it][dt][r];
                        redC[i][d] = (w == 0) ? v : (redC[i][d] + v);
                    }
        }
    }
    __syncthreads();
    // write ctxA in A-fragment order: m = b*Nn+gi, k = h*64+d
#pragma unroll
    for (int rep = 0; rep < 2; ++rep) {
        int s2 = tid + rep * 256;          // < 512 : i(6b) x dc(3b)
        int i = s2 >> 3, dc = s2 & 7;
        int gi = ib * 64 + i;
        if (gi < Nn) {
            int m = b * Nn + gi;
            float den = red16s[0][i] + red16s[1][i] + red16s[2][i] + red16s[3][i];
            float dv = 1.f / (den + 1e-8f);
            const float* src = &redC[i][dc * 8];
            uint4 pk;
            pk.x = (unsigned)f2bf(src[0] * dv) | ((unsigned)f2bf(src[1] * dv) << 16);
            pk.y = (unsigned)f2bf(src[2] * dv) | ((unsigned)f2bf(src[3] * dv) << 16);
            pk.z = (unsigned)f2bf(src[4] * dv) | ((unsigned)f2bf(src[5] * dv) << 16);
            pk.w = (unsigned)f2bf(src[6] * dv) | ((unsigned)f2bf(src[7] * dv) << 16);
            int kc2 = h * 2 + (dc >> 2);
            int q2 = dc & 3;
            size_t idx = (((size_t)(kc2 * MT16 + (m >> 4))) * 64 + q2 * 16 + (m & 15)) * 8;
            *(uint4*)&ctxA[idx] = pk;
        }
    }
}

// ---------------------------------------------------------------------------
extern "C" void kernel_launch(void* const* d_in, const int* in_sizes, int n_in,
                              void* d_out, int out_size, void* d_ws, size_t ws_size,
                              hipStream_t stream) {
    const float* x     = (const float*)d_in[0];
    const float* ucb   = (const float*)d_in[1];
    const float* Wqkv  = (const float*)d_in[2];
    const float* Wproj = (const float*)d_in[3];
    const float* bproj = (const float*)d_in[4];
    const int*   counter = (const int*)d_in[5];

    unsigned short* qB = (unsigned short*)d_ws;      // 3,342,336 sh
    unsigned short* kF = qB + 3342336;               // 3,538,944 sh
    unsigned short* vF = kF + 3538944;               // 3,538,944 sh
    float* keepP    = (float*)(vF + 3538944);        // 4608 f
    float* cnt_b    = keepP + 4608;                  // 4608 f
    unsigned short* ctxA = (unsigned short*)(cnt_b + 4608);  // 3,244,032 sh
    unsigned short* xA   = ctxA + 3244032;           // 3,244,032 sh
    unsigned short* WB   = xA + 3244032;             // 1,769,472 sh
    unsigned short* WpB  = WB + 1769472;             // 589,824 sh
    float* colsum_part = (float*)(WpB + 589824);     // 1,824,768 f
    float* scoreF = colsum_part + 1824768;           // 4,096 f

    float* out  = (float*)d_out;                     // [B,N,C]
    float* out2 = out + 3148800;                     // [H,N]

    cast_all<<<dim3(CAST_X_BLK + CAST_WQKV_BLK + CAST_WPROJ_BLK), dim3(256), 0, stream>>>(
        x, Wqkv, Wproj, xA, WB, WpB);
    gemm_mfma<4, 0><<<dim3(33, 18), dim3(256), 0, stream>>>(
        xA, WB, 144, qB, kF, vF, nullptr, nullptr);
    attn_colsum_mfma<<<dim3(8 * 198), dim3(256), 0, stream>>>(qB, kF, colsum_part);
    colsum_reduce<<<dim3(Bb, 32), dim3(256), 0, stream>>>(colsum_part, ucb, counter, scoreF);
    ucb_topk<<<dim3(Bb), dim3(1024), 0, stream>>>(scoreF, keepP, cnt_b);
    attn_ctx_mfma<<<dim3(8 * 102), dim3(256), 0, stream>>>(qB, kF, vF, keepP, cnt_b, ctxA, out2);
    gemm_mfma<2, 1><<<dim3(33, 12), dim3(256), 0, stream>>>(
        ctxA, WpB, 48, nullptr, nullptr, nullptr, out, bproj);
}